// Round 1
// baseline (268.581 us; speedup 1.0000x reference)
//
#include <hip/hip_runtime.h>

#define OBS_LEN 20
#define PRED_LEN 30
#define MBLK 32

typedef __attribute__((ext_vector_type(8))) short bf16x8;
typedef __attribute__((ext_vector_type(4))) float f32x4;

__device__ __forceinline__ unsigned short f2bf(float x){
  unsigned int u = __float_as_uint(x);
  u = u + 0x7FFFu + ((u >> 16) & 1u);
  return (unsigned short)(u >> 16);
}

__device__ __forceinline__ float sigm(float x){
  return __builtin_amdgcn_rcpf(1.0f + __expf(-x));
}
__device__ __forceinline__ float tanh_(float x){
  return 1.0f - 2.0f*__builtin_amdgcn_rcpf(__expf(2.0f*x) + 1.0f);
}

__global__ __launch_bounds__(512, 2) void traj_kernel(
    const float* __restrict__ img, const float* __restrict__ obs_pos,
    const int* __restrict__ hist, const float* __restrict__ rel,
    const float* __restrict__ h0, const float* __restrict__ W_ih,
    const float* __restrict__ W_hh, const float* __restrict__ b_ih,
    const float* __restrict__ b_hh, const float* __restrict__ eW,
    const float* __restrict__ eb, const float* __restrict__ pW,
    const float* __restrict__ pb, float* __restrict__ out)
{
  // xh: [m][k] bf16, k<64 = x_emb, 64..191 = h. stride 200 (pad: 2-way bank alias only)
  __shared__ unsigned short xh[MBLK*200];
  __shared__ float hf[MBLK*132];      // f32 h for disp reduction (pad 4)
  __shared__ float relL[MBLK*40];     // obs_pos_rel for the block's samples
  __shared__ float pwL[2*128];        // pred_W[:, :128]
  __shared__ float eW0[64], eW1[64], ebL[64];
  __shared__ float dispL[MBLK*2];
  __shared__ float imgcL[MBLK*2];

  const int tid  = threadIdx.x;
  const int wv   = tid >> 6;
  const int lane = tid & 63;
  const int q    = lane >> 4;
  const int i    = lane & 15;
  const int j    = wv*16 + i;            // hidden unit owned by this lane
  const int g0   = blockIdx.x * MBLK;

  // ---- cooperative staging ----
  for (int idx = tid; idx < MBLK*40; idx += 512) relL[idx] = rel[g0*40 + idx];
  if (tid < 256) pwL[tid] = pW[(tid >> 7)*2176 + (tid & 127)];
  if (tid < 64){ eW0[tid] = eW[tid*2]; eW1[tid] = eW[tid*2+1]; ebL[tid] = eb[tid]; }

  // ---- img_embedding @ pred_W[:,128:].T  (once; constant over pred steps) ----
  {
    int m = tid >> 4, i16 = tid & 15;
    const float* row = img + (size_t)(g0 + m)*2048 + i16*128;
    const float* p0  = pW + 128 + i16*128;
    const float* p1  = pW + 2176 + 128 + i16*128;
    float s0 = 0.f, s1 = 0.f;
    #pragma unroll
    for (int v = 0; v < 32; v++){
      float4 a  = ((const float4*)row)[v];
      float4 w0 = ((const float4*)p0)[v];
      float4 w1 = ((const float4*)p1)[v];
      s0 += a.x*w0.x + a.y*w0.y + a.z*w0.z + a.w*w0.w;
      s1 += a.x*w1.x + a.y*w1.y + a.z*w1.z + a.w*w1.w;
    }
    #pragma unroll
    for (int msk = 1; msk < 16; msk <<= 1){
      s0 += __shfl_xor(s0, msk);
      s1 += __shfl_xor(s1, msk);
    }
    if (i16 == 0){ imgcL[m*2] = s0; imgcL[m*2+1] = s1; }
  }

  // ---- per-lane persistent state ----
  float h0j = h0[j];
  float bias_s[4];
  #pragma unroll
  for (int nt = 0; nt < 4; nt++) bias_s[nt] = b_ih[nt*128 + j] + b_hh[nt*128 + j];

  int   hist_s[8];
  float c_s[8], h_s[8];
  #pragma unroll
  for (int mt = 0; mt < 2; mt++)
    #pragma unroll
    for (int r = 0; r < 4; r++){
      int m = mt*16 + q*4 + r;
      hist_s[mt*4+r] = hist[g0 + m];
      c_s[mt*4+r] = h0j; h_s[mt*4+r] = h0j;
      xh[m*200 + 64 + j] = f2bf(h0j);
      hf[m*132 + j] = h0j;
    }

  // ---- weight B-fragments, fp32 -> bf16, register-resident (96 VGPR/lane) ----
  // B layout: lane holds W[n = ntile_row + (lane&15)][k = kt*32 + q*8 + jj]
  bf16x8 Bf[4][6];
  #pragma unroll
  for (int nt = 0; nt < 4; nt++){
    int row = nt*128 + j;
    #pragma unroll
    for (int kt = 0; kt < 6; kt++){
      const float* src = (kt < 2) ? (W_ih + row*64  + kt*32      + q*8)
                                  : (W_hh + row*128 + (kt-2)*32  + q*8);
      float4 lo = ((const float4*)src)[0];
      float4 hi = ((const float4*)src)[1];
      bf16x8 tf;
      tf[0]=(short)f2bf(lo.x); tf[1]=(short)f2bf(lo.y); tf[2]=(short)f2bf(lo.z); tf[3]=(short)f2bf(lo.w);
      tf[4]=(short)f2bf(hi.x); tf[5]=(short)f2bf(hi.y); tf[6]=(short)f2bf(hi.z); tf[7]=(short)f2bf(hi.w);
      Bf[nt][kt] = tf;
    }
  }

  // disp-phase identity (leader lanes i8==0 own (sample dm, coord dod))
  const int dm  = tid >> 4;
  const int dod = (tid >> 3) & 1;
  float pos_r = obs_pos[(size_t)(g0 + dm)*40 + 38 + dod];   // obs_pos[:, 19, :]
  float pb_r  = pb[dod];
  size_t out_base = (size_t)(g0 + dm)*60 + dod;

  __syncthreads();
  float imgc_r = imgcL[dm*2 + dod];

  f32x4 acc[2][4];

  for (int step = 0; step < 49; step++){
    const bool obs = (step < 19);
    const int  t   = step + 1;            // obs time index 1..19
    if (!obs){
      __syncthreads();                    // prev-step h writes -> hf reads
      int i8 = tid & 7;
      const float* hrow = &hf[dm*132 + i8*16];
      const float* prow = &pwL[dod*128 + i8*16];
      float s = 0.f;
      #pragma unroll
      for (int v = 0; v < 4; v++){
        float4 h4 = ((const float4*)hrow)[v];
        float4 p4 = ((const float4*)prow)[v];
        s += h4.x*p4.x + h4.y*p4.y + h4.z*p4.z + h4.w*p4.w;
      }
      s += __shfl_xor(s, 1); s += __shfl_xor(s, 2); s += __shfl_xor(s, 4);
      if (i8 == 0){
        float d = s + imgc_r + pb_r;
        pos_r += d;
        out[out_base + (size_t)(step - 19)*2] = pos_r;
        dispL[dm*2 + dod] = d;
      }
    }
    __syncthreads();
    // ---- x_emb = relu(in @ embed_W.T + embed_b), packed bf16 into xh[:, 0:64] ----
    {
      int m  = tid >> 4;
      int e0 = (tid & 15) << 2;
      float r0, r1;
      if (obs){ r0 = relL[m*40 + t*2]; r1 = relL[m*40 + t*2 + 1]; }
      else    { r0 = dispL[m*2];       r1 = dispL[m*2 + 1]; }
      float a0 = fmaxf(0.f, r0*eW0[e0+0] + r1*eW1[e0+0] + ebL[e0+0]);
      float a1 = fmaxf(0.f, r0*eW0[e0+1] + r1*eW1[e0+1] + ebL[e0+1]);
      float a2 = fmaxf(0.f, r0*eW0[e0+2] + r1*eW1[e0+2] + ebL[e0+2]);
      float a3 = fmaxf(0.f, r0*eW0[e0+3] + r1*eW1[e0+3] + ebL[e0+3]);
      unsigned int pk0 = (unsigned int)f2bf(a0) | ((unsigned int)f2bf(a1) << 16);
      unsigned int pk1 = (unsigned int)f2bf(a2) | ((unsigned int)f2bf(a3) << 16);
      *((uint2*)&xh[m*200 + e0]) = make_uint2(pk0, pk1);
    }
    __syncthreads();
    // ---- gates = [x|h] @ [W_ih|W_hh].T + b  via MFMA 16x16x32 bf16 ----
    #pragma unroll
    for (int mt = 0; mt < 2; mt++){
      bf16x8 A[6];
      int mrow = mt*16 + i;
      #pragma unroll
      for (int kt = 0; kt < 6; kt++)
        A[kt] = *((const bf16x8*)&xh[mrow*200 + kt*32 + q*8]);
      #pragma unroll
      for (int nt = 0; nt < 4; nt++)
        acc[mt][nt] = (f32x4){bias_s[nt], bias_s[nt], bias_s[nt], bias_s[nt]};
      #pragma unroll
      for (int kt = 0; kt < 6; kt++)
        #pragma unroll
        for (int nt = 0; nt < 4; nt++)
          acc[mt][nt] = __builtin_amdgcn_mfma_f32_16x16x32_bf16(A[kt], Bf[nt][kt], acc[mt][nt], 0, 0, 0);
    }
    __syncthreads();
    // ---- nonlinearity + state update (c in registers; D row = q*4+r, col = i) ----
    #pragma unroll
    for (int mt = 0; mt < 2; mt++)
      #pragma unroll
      for (int r = 0; r < 4; r++){
        int sl = mt*4 + r;
        float ig = acc[mt][0][r];
        float fg = acc[mt][1][r];
        float gg = acc[mt][2][r];
        float og = acc[mt][3][r];
        float c2 = sigm(fg)*c_s[sl] + sigm(ig)*tanh_(gg);
        float h2 = sigm(og)*tanh_(c2);
        if (obs){
          bool upd = hist_s[sl] > (OBS_LEN - t);
          c2 = upd ? c2 : c_s[sl];
          h2 = upd ? h2 : h_s[sl];
        }
        c_s[sl] = c2; h_s[sl] = h2;
        int m = mt*16 + q*4 + r;
        xh[m*200 + 64 + j] = f2bf(h2);
        hf[m*132 + j] = h2;
      }
  }
}

extern "C" void kernel_launch(void* const* d_in, const int* in_sizes, int n_in,
                              void* d_out, int out_size, void* d_ws, size_t ws_size,
                              hipStream_t stream){
  const float* img     = (const float*)d_in[0];
  const float* obs_pos = (const float*)d_in[1];
  const int*   hist    = (const int*)d_in[2];
  const float* rel     = (const float*)d_in[3];
  const float* h0      = (const float*)d_in[4];
  const float* W_ih    = (const float*)d_in[5];
  const float* W_hh    = (const float*)d_in[6];
  const float* b_ih    = (const float*)d_in[7];
  const float* b_hh    = (const float*)d_in[8];
  const float* eW      = (const float*)d_in[9];
  const float* eb      = (const float*)d_in[10];
  const float* pW      = (const float*)d_in[11];
  const float* pb      = (const float*)d_in[12];
  float* out = (float*)d_out;
  hipLaunchKernelGGL(traj_kernel, dim3(8192/MBLK), dim3(512), 0, stream,
                     img, obs_pos, hist, rel, h0, W_ih, W_hh, b_ih, b_hh,
                     eW, eb, pW, pb, out);
}

// Round 2
// 268.567 us; speedup vs baseline: 1.0001x; 1.0001x over previous
//
#include <hip/hip_runtime.h>

#define MBLK 32

typedef __attribute__((ext_vector_type(8))) short bf16x8;
typedef __attribute__((ext_vector_type(4))) float f32x4;

__device__ __forceinline__ unsigned short f2bf(float x){
  unsigned int u = __float_as_uint(x);
  u = u + 0x7FFFu + ((u >> 16) & 1u);
  return (unsigned short)(u >> 16);
}
__device__ __forceinline__ float bf2f(unsigned short s){
  return __uint_as_float(((unsigned int)s) << 16);
}
__device__ __forceinline__ float sigm(float x){
  return __builtin_amdgcn_rcpf(1.0f + __expf(-x));
}
__device__ __forceinline__ float tanh_(float x){
  return 1.0f - 2.0f*__builtin_amdgcn_rcpf(__expf(2.0f*x) + 1.0f);
}

// Double-buffered [x(64) | h(128)] bf16 tile, row stride 200 shorts
// (= 100 dwords ≡ 4 mod 32 -> balanced banks for b128 frag reads; 400 B rows keep
// 16-B alignment for ds_read_b128).
// One __syncthreads per obs step, two per pred step:
//   step s: barrier; [pred: disp+x_emb -> xh[b]; barrier]; MFMA reads xh[b];
//           obs: x_emb(t+1) -> xh[b^1]; nonlin; h2 -> xh[b^1]; b^=1.
__global__ __launch_bounds__(512, 2) void traj_kernel(
    const float* __restrict__ img, const float* __restrict__ obs_pos,
    const int* __restrict__ hist, const float* __restrict__ rel,
    const float* __restrict__ h0, const float* __restrict__ W_ih,
    const float* __restrict__ W_hh, const float* __restrict__ b_ih,
    const float* __restrict__ b_hh, const float* __restrict__ eW,
    const float* __restrict__ eb, const float* __restrict__ pW,
    const float* __restrict__ pb, float* __restrict__ out)
{
  __shared__ unsigned short xh[2][MBLK*200];
  __shared__ float relL[MBLK*40];
  __shared__ float pwL[256];          // pred_W[:, :128]
  __shared__ float eW0[64], eW1[64], ebL[64];
  __shared__ float imgcL[MBLK*2];

  const int tid  = threadIdx.x;
  const int wv   = tid >> 6;
  const int lane = tid & 63;
  const int q    = lane >> 4;
  const int i    = lane & 15;
  const int j    = wv*16 + i;          // hidden unit owned by this lane
  const int g0   = blockIdx.x * MBLK;

  // ---- cooperative staging ----
  for (int idx = tid; idx < MBLK*40; idx += 512) relL[idx] = rel[g0*40 + idx];
  if (tid < 256) pwL[tid] = pW[(tid >> 7)*2176 + (tid & 127)];
  if (tid < 64){ eW0[tid] = eW[tid*2]; eW1[tid] = eW[tid*2+1]; ebL[tid] = eb[tid]; }

  // ---- img_embedding @ pred_W[:,128:].T  (once; constant over pred steps) ----
  {
    int m = tid >> 4, i16 = tid & 15;
    const float* row = img + (size_t)(g0 + m)*2048 + i16*128;
    const float* p0  = pW + 128 + i16*128;
    const float* p1  = pW + 2176 + 128 + i16*128;
    float s0 = 0.f, s1 = 0.f;
    #pragma unroll
    for (int v = 0; v < 32; v++){
      float4 a  = ((const float4*)row)[v];
      float4 w0 = ((const float4*)p0)[v];
      float4 w1 = ((const float4*)p1)[v];
      s0 += a.x*w0.x + a.y*w0.y + a.z*w0.z + a.w*w0.w;
      s1 += a.x*w1.x + a.y*w1.y + a.z*w1.z + a.w*w1.w;
    }
    #pragma unroll
    for (int msk = 1; msk < 16; msk <<= 1){
      s0 += __shfl_xor(s0, msk);
      s1 += __shfl_xor(s1, msk);
    }
    if (i16 == 0){ imgcL[m*2] = s0; imgcL[m*2+1] = s1; }
  }

  // ---- per-lane persistent state ----
  float h0j = h0[j];
  float bias_s[4];
  #pragma unroll
  for (int nt = 0; nt < 4; nt++) bias_s[nt] = b_ih[nt*128 + j] + b_hh[nt*128 + j];

  int   hist_s[8];
  float c_s[8], h_s[8];
  #pragma unroll
  for (int mt = 0; mt < 2; mt++)
    #pragma unroll
    for (int r = 0; r < 4; r++){
      int m = mt*16 + q*4 + r;
      hist_s[mt*4+r] = hist[g0 + m];
      c_s[mt*4+r] = h0j; h_s[mt*4+r] = h0j;
      xh[0][m*200 + 64 + j] = f2bf(h0j);
    }

  // ---- weight B-fragments, fp32 -> bf16, register-resident ----
  bf16x8 Bf[4][6];
  #pragma unroll
  for (int nt = 0; nt < 4; nt++){
    int row = nt*128 + j;
    #pragma unroll
    for (int kt = 0; kt < 6; kt++){
      const float* src = (kt < 2) ? (W_ih + row*64  + kt*32      + q*8)
                                  : (W_hh + row*128 + (kt-2)*32  + q*8);
      float4 lo = ((const float4*)src)[0];
      float4 hi = ((const float4*)src)[1];
      bf16x8 tf;
      tf[0]=(short)f2bf(lo.x); tf[1]=(short)f2bf(lo.y); tf[2]=(short)f2bf(lo.z); tf[3]=(short)f2bf(lo.w);
      tf[4]=(short)f2bf(hi.x); tf[5]=(short)f2bf(hi.y); tf[6]=(short)f2bf(hi.z); tf[7]=(short)f2bf(hi.w);
      Bf[nt][kt] = tf;
    }
  }

  // disp-phase identity: 16 lanes per sample
  const int dm  = tid >> 4;            // sample 0..31
  const int i16 = tid & 15;
  float pos_r = 0.f;
  if (i16 < 2) pos_r = obs_pos[(size_t)(g0 + dm)*40 + 38 + i16];

  __syncthreads();   // staging (relL, eW*, imgcL) visible

  const float imgc0 = imgcL[dm*2], imgc1 = imgcL[dm*2+1];
  const float pb0 = pb[0], pb1 = pb[1];

  // ---- x_emb(t=1) into xh[0] ----
  {
    int e0 = i16 << 2;
    float r0 = relL[dm*40 + 2], r1 = relL[dm*40 + 3];
    float a0 = fmaxf(0.f, r0*eW0[e0+0] + r1*eW1[e0+0] + ebL[e0+0]);
    float a1 = fmaxf(0.f, r0*eW0[e0+1] + r1*eW1[e0+1] + ebL[e0+1]);
    float a2 = fmaxf(0.f, r0*eW0[e0+2] + r1*eW1[e0+2] + ebL[e0+2]);
    float a3 = fmaxf(0.f, r0*eW0[e0+3] + r1*eW1[e0+3] + ebL[e0+3]);
    unsigned int pk0 = (unsigned int)f2bf(a0) | ((unsigned int)f2bf(a1) << 16);
    unsigned int pk1 = (unsigned int)f2bf(a2) | ((unsigned int)f2bf(a3) << 16);
    *((uint2*)&xh[0][dm*200 + e0]) = make_uint2(pk0, pk1);
  }

  int b = 0;
  f32x4 acc[2][4];

  for (int step = 0; step < 49; step++){
    const bool obs = (step < 19);
    __syncthreads();     // prev step's writes into xh[b] visible

    if (!obs){
      // ---- disp = h @ pwL + imgc + pb, fused butterfly; then x_emb -> xh[b] ----
      bf16x8 hv = *((const bf16x8*)&xh[b][dm*200 + 64 + i16*8]);
      float s0 = 0.f, s1 = 0.f;
      #pragma unroll
      for (int u = 0; u < 8; u++){
        float hfv = bf2f((unsigned short)hv[u]);
        s0 += hfv * pwL[i16*8 + u];
        s1 += hfv * pwL[128 + i16*8 + u];
      }
      s0 += __shfl_xor(s0, 1); s1 += __shfl_xor(s1, 1);
      s0 += __shfl_xor(s0, 2); s1 += __shfl_xor(s1, 2);
      s0 += __shfl_xor(s0, 4); s1 += __shfl_xor(s1, 4);
      s0 += __shfl_xor(s0, 8); s1 += __shfl_xor(s1, 8);
      float d0 = s0 + imgc0 + pb0;
      float d1 = s1 + imgc1 + pb1;
      if (i16 < 2){
        pos_r += (i16 == 0) ? d0 : d1;
        out[(size_t)(g0 + dm)*60 + (size_t)(step - 19)*2 + i16] = pos_r;
      }
      int e0 = i16 << 2;
      float a0 = fmaxf(0.f, d0*eW0[e0+0] + d1*eW1[e0+0] + ebL[e0+0]);
      float a1 = fmaxf(0.f, d0*eW0[e0+1] + d1*eW1[e0+1] + ebL[e0+1]);
      float a2 = fmaxf(0.f, d0*eW0[e0+2] + d1*eW1[e0+2] + ebL[e0+2]);
      float a3 = fmaxf(0.f, d0*eW0[e0+3] + d1*eW1[e0+3] + ebL[e0+3]);
      unsigned int pk0 = (unsigned int)f2bf(a0) | ((unsigned int)f2bf(a1) << 16);
      unsigned int pk1 = (unsigned int)f2bf(a2) | ((unsigned int)f2bf(a3) << 16);
      *((uint2*)&xh[b][dm*200 + e0]) = make_uint2(pk0, pk1);
      __syncthreads();   // x_emb visible before MFMA reads
    }

    // ---- gates = [x|h] @ [W_ih|W_hh].T + b  via MFMA 16x16x32 bf16 ----
    #pragma unroll
    for (int mt = 0; mt < 2; mt++){
      bf16x8 A[6];
      int mrow = mt*16 + i;
      #pragma unroll
      for (int kt = 0; kt < 6; kt++)
        A[kt] = *((const bf16x8*)&xh[b][mrow*200 + kt*32 + q*8]);
      #pragma unroll
      for (int nt = 0; nt < 4; nt++)
        acc[mt][nt] = (f32x4){bias_s[nt], bias_s[nt], bias_s[nt], bias_s[nt]};
      #pragma unroll
      for (int kt = 0; kt < 6; kt++)
        #pragma unroll
        for (int nt = 0; nt < 4; nt++)
          acc[mt][nt] = __builtin_amdgcn_mfma_f32_16x16x32_bf16(A[kt], Bf[nt][kt], acc[mt][nt], 0, 0, 0);
    }

    // ---- obs: next step's x_emb (depends only on relL) -> xh[b^1] ----
    if (obs && step < 18){
      int tt = step + 2;               // t+1
      int e0 = i16 << 2;
      float r0 = relL[dm*40 + tt*2], r1 = relL[dm*40 + tt*2 + 1];
      float a0 = fmaxf(0.f, r0*eW0[e0+0] + r1*eW1[e0+0] + ebL[e0+0]);
      float a1 = fmaxf(0.f, r0*eW0[e0+1] + r1*eW1[e0+1] + ebL[e0+1]);
      float a2 = fmaxf(0.f, r0*eW0[e0+2] + r1*eW1[e0+2] + ebL[e0+2]);
      float a3 = fmaxf(0.f, r0*eW0[e0+3] + r1*eW1[e0+3] + ebL[e0+3]);
      unsigned int pk0 = (unsigned int)f2bf(a0) | ((unsigned int)f2bf(a1) << 16);
      unsigned int pk1 = (unsigned int)f2bf(a2) | ((unsigned int)f2bf(a3) << 16);
      *((uint2*)&xh[b^1][dm*200 + e0]) = make_uint2(pk0, pk1);
    }

    // ---- nonlinearity + state update; h2 -> xh[b^1] ----
    #pragma unroll
    for (int mt = 0; mt < 2; mt++)
      #pragma unroll
      for (int r = 0; r < 4; r++){
        int sl = mt*4 + r;
        float ig = acc[mt][0][r];
        float fg = acc[mt][1][r];
        float gg = acc[mt][2][r];
        float og = acc[mt][3][r];
        float c2 = sigm(fg)*c_s[sl] + sigm(ig)*tanh_(gg);
        float h2 = sigm(og)*tanh_(c2);
        if (obs){
          bool upd = hist_s[sl] > (19 - step);
          c2 = upd ? c2 : c_s[sl];
          h2 = upd ? h2 : h_s[sl];
        }
        c_s[sl] = c2; h_s[sl] = h2;
        int m = mt*16 + q*4 + r;
        xh[b^1][m*200 + 64 + j] = f2bf(h2);
      }

    b ^= 1;
  }
}

extern "C" void kernel_launch(void* const* d_in, const int* in_sizes, int n_in,
                              void* d_out, int out_size, void* d_ws, size_t ws_size,
                              hipStream_t stream){
  const float* img     = (const float*)d_in[0];
  const float* obs_pos = (const float*)d_in[1];
  const int*   hist    = (const int*)d_in[2];
  const float* rel     = (const float*)d_in[3];
  const float* h0      = (const float*)d_in[4];
  const float* W_ih    = (const float*)d_in[5];
  const float* W_hh    = (const float*)d_in[6];
  const float* b_ih    = (const float*)d_in[7];
  const float* b_hh    = (const float*)d_in[8];
  const float* eW      = (const float*)d_in[9];
  const float* eb      = (const float*)d_in[10];
  const float* pW      = (const float*)d_in[11];
  const float* pb      = (const float*)d_in[12];
  float* out = (float*)d_out;
  hipLaunchKernelGGL(traj_kernel, dim3(8192/MBLK), dim3(512), 0, stream,
                     img, obs_pos, hist, rel, h0, W_ih, W_hh, b_ih, b_hh,
                     eW, eb, pW, pb, out);
}